// Round 1
// baseline (413.086 us; speedup 1.0000x reference)
//
#include <hip/hip_runtime.h>

// Problem constants (fixed by setup_inputs)
#define BB 4
#define CC 64      // feature channels
#define KK 16      // neighbors
#define NN 16384   // points
#define NTB 128    // points per block = 2 independent 64-point pairs

typedef __attribute__((ext_vector_type(8))) short short8;     // 8 bf16 (MFMA A/B)
typedef __attribute__((ext_vector_type(4))) float floatx4;    // MFMA C/D
typedef __attribute__((ext_vector_type(2))) _Float16 half2v;  // packed f16 pair

__device__ __forceinline__ unsigned short f2bf_rtne(float x) {  // RTNE f32->bf16
    unsigned u = __builtin_bit_cast(unsigned, x);
    u += 0x7FFFu + ((u >> 16) & 1u);
    return (unsigned short)(u >> 16);
}

// pack two f32 into bf16x2 (round-half-up via +0x8000, then v_perm byte-select)
__device__ __forceinline__ unsigned pack_bf16x2(float lo, float hi) {
    unsigned a = __builtin_bit_cast(unsigned, lo) + 0x8000u;
    unsigned b = __builtin_bit_cast(unsigned, hi) + 0x8000u;
    return __builtin_amdgcn_perm(b, a, 0x07060302u);  // {b.hi16, a.hi16}
}

// cvt_pkrtz returns __fp16x2; bit_cast to _Float16x2 for fdot2
__device__ __forceinline__ half2v cvt2h(float a, float b) {
    return __builtin_bit_cast(half2v, __builtin_amdgcn_cvt_pkrtz(a, b));
}

#if __has_builtin(__builtin_amdgcn_fdot2)
#define DOT2(a, b, c) __builtin_amdgcn_fdot2((a), (b), (c), false)
#else
__device__ __forceinline__ float dot2_fb(half2v a, half2v b, float c) {
    return fmaf((float)a[0], (float)b[0], fmaf((float)a[1], (float)b[1], c));
}
#define DOT2(a, b, c) dot2_fb((a), (b), (c))
#endif

// ---------------------------------------------------------------------------
// One-time: repack lin_w (f32 [64][1024]) into bf16 MFMA B-fragments in the
// exact per-wave load order: [chunk ci][kk][nt][lane]{8 bf16}. 128 KB, L2-hot.
// ---------------------------------------------------------------------------
__global__ __launch_bounds__(256)
void prep_bfrag(const float* __restrict__ lin_w, unsigned short* __restrict__ bfrag)
{
    const int tid  = blockIdx.x * 256 + threadIdx.x;  // 0..8191
    const int lane = tid & 63;
    const int g    = tid >> 6;            // 0..127 = (ci,kk,nt)
    const int ci   = g >> 4;
    const int kk   = (g >> 2) & 3;
    const int nt   = g & 3;
    const int r    = lane & 15;
    const int sq   = lane >> 4;

    const float* src = lin_w + (size_t)(nt * 16 + r) * 1024 + ci * 128 + kk * 32 + sq * 8;
    unsigned short v[8];
    #pragma unroll
    for (int j = 0; j < 8; ++j) v[j] = f2bf_rtne(src[j]);
    *(uint4*)(bfrag + ((size_t)g * 64 + lane) * 8) = *(const uint4*)v;
}

// ---------------------------------------------------------------------------
// Fused weightnet + aggregation + linear(MFMA).
// Block = 256 thr = 4 waves = 2 independent 64-point PAIRS.
// Pair P = waves {2P, 2P+1}; within a pair, wave h computes weightnet/agg for
// o in [8h, 8h+8).
// s_a holds agg in A-FRAGMENT-NATIVE layout [Mt][kk][r][sq] (uint4 chunks,
// Mt stride 257) double-buffered per pair.
//
// NEW this round: cross-barrier software pipeline. Region ci executes
//   channel_section(ci+1)  -> s_a[P][(ci+1)&1]   (long VALU + pv refills)
//   MFMA_section(ci)       <- s_a[P][ci&1]       (bf_c already ~1.4k cy in flight)
//   pre-issue bf_c(ci+1, kk=0); lgkm-only barrier.
// Buffer disjointness: my writes target the opposite buffer from all reads of
// ci; partner's reads of buf ci&1 completed before the previous barrier; sq
// slots are wave-disjoint. vmcnt is never drained at barriers, so pv refills
// and B-fragment loads stay in flight across regions — kk=0 B-stall vanishes
// and the pv pipeline gains a full MFMA section of extra latency cover.
// lin_b dropped: training-mode BN cancels per-channel shifts.
// ---------------------------------------------------------------------------
__global__ __launch_bounds__(256, 2)
void fused_main(const float* __restrict__ points,
                const float* __restrict__ coordinate,
                const float* __restrict__ w1,
                const float* __restrict__ b1,
                const unsigned short* __restrict__ bfrag,
                float* __restrict__ y_out)   // [B][C][N] pre-BN
{
    __shared__ uint4 s_a[2][2][4 * 257];  // [pair][buf][Mt*257 + kk*64 + r*4 + sq]

    const int t    = threadIdx.x;
    const int lane = t & 63;
    const int wv   = __builtin_amdgcn_readfirstlane(t >> 6);
    const int P    = wv >> 1;      // pair id
    const int h    = wv & 1;       // o-half within pair
    const int r    = lane & 15;
    const int sq   = lane >> 4;

    const int bid = blockIdx.x;
    const int b   = bid >> 7;                    // 128 blocks per batch
    const int n0  = (bid & 127) * NTB + P * 64;  // pair's point base in batch

    // ---- weightnet into f16-pair registers: wh[j][kp], o = 8h + j
    half2v wh[8][8];
    {
        const float* coordB = coordinate + (size_t)b * 3 * KK * NN + n0 + lane;
        float c0[KK], c1[KK], c2[KK];
        #pragma unroll
        for (int k = 0; k < KK; ++k) {
            c0[k] = coordB[(0 * KK + k) * NN];
            c1[k] = coordB[(1 * KK + k) * NN];
            c2[k] = coordB[(2 * KK + k) * NN];
        }
        #pragma unroll
        for (int j = 0; j < 8; ++j) {
            const int o = 8 * h + j;
            const float w1x = w1[o * 3 + 0];
            const float w1y = w1[o * 3 + 1];
            const float w1z = w1[o * 3 + 2];
            const float bo  = b1[o];
            #pragma unroll
            for (int kp = 0; kp < 8; ++kp) {
                float v0 = fmaf(w1x, c0[2 * kp],     fmaf(w1y, c1[2 * kp],     fmaf(w1z, c2[2 * kp],     bo)));
                float v1 = fmaf(w1x, c0[2 * kp + 1], fmaf(w1y, c1[2 * kp + 1], fmaf(w1z, c2[2 * kp + 1], bo)));
                wh[j][kp] = cvt2h(fmaxf(v0, 0.0f), fmaxf(v1, 0.0f));
            }
        }
    }

    floatx4 acc[2][4];
    #pragma unroll
    for (int m = 0; m < 2; ++m)
        #pragma unroll
        for (int nt = 0; nt < 4; ++nt) acc[m][nt] = (floatx4){0.f, 0.f, 0.f, 0.f};

    const float* pB = points + (size_t)b * CC * KK * NN + n0 + lane;  // lane's column

    // ---- prime the distance-4 points pipeline (channels 0..3)
    float pv[4][16];
    #pragma unroll
    for (int d = 0; d < 4; ++d)
        #pragma unroll
        for (int k = 0; k < KK; ++k)
            pv[d][k] = pB[((size_t)d * KK + k) * NN];

    // ---- channel section for chunk c_: consumes pv, refills, writes s_a[P][c_&1]
#define CHANNEL_SECTION(CARG)                                                   \
    {                                                                           \
        const int c_ = (CARG);                                                  \
        uint4* saW = &s_a[P][c_ & 1][0];                                        \
        _Pragma("unroll")                                                       \
        for (int cl = 0; cl < 8; ++cl) {                                        \
            const int cc   = c_ * 8 + cl;                                       \
            const int slot = cl & 3;        /* (c_*8+cl)&3 == cl&3 */           \
            half2v ph[8];                                                       \
            _Pragma("unroll")                                                   \
            for (int kp = 0; kp < 8; ++kp)                                      \
                ph[kp] = cvt2h(pv[slot][2 * kp], pv[slot][2 * kp + 1]);         \
            {                                                                   \
                const int cp = (cc + 4 < CC) ? (cc + 4) : (CC - 1);             \
                _Pragma("unroll")                                               \
                for (int k = 0; k < KK; ++k)                                    \
                    pv[slot][k] = pB[((size_t)cp * KK + k) * NN];               \
            }                                                                   \
            float a8[8];                                                        \
            _Pragma("unroll")                                                   \
            for (int j = 0; j < 8; ++j) {                                       \
                float a = 0.f;                                                  \
                _Pragma("unroll")                                               \
                for (int kp = 0; kp < 8; ++kp) a = DOT2(ph[kp], wh[j][kp], a);  \
                a8[j] = a;                                                      \
            }                                                                   \
            uint4 pk;                                                           \
            pk.x = pack_bf16x2(a8[0], a8[1]);                                   \
            pk.y = pack_bf16x2(a8[2], a8[3]);                                   \
            pk.z = pack_bf16x2(a8[4], a8[5]);                                   \
            pk.w = pack_bf16x2(a8[6], a8[7]);                                   \
            saW[(lane >> 4) * 257 + (cl >> 1) * 64 + (lane & 15) * 4            \
                + (cl & 1) * 2 + h] = pk;                                       \
        }                                                                       \
    }

    // ---- prologue region: channel(0), B-frags (0,kk=0), barrier
    CHANNEL_SECTION(0)

    uint4 bf_c[4];
    #pragma unroll
    for (int nt = 0; nt < 4; ++nt)
        bf_c[nt] = *(const uint4*)(bfrag + ((((size_t)0 * 4 + 0) * 4 + nt) * 64 + lane) * 8);

    // LDS-only barrier: lgkmcnt(0) for s_a visibility, NO vmcnt drain
    asm volatile("s_waitcnt lgkmcnt(0)\n\ts_barrier" ::: "memory");

    for (int ci = 0; ci < 8; ++ci) {
        // 1) next chunk's channel work first: its ds_writes + pv refills issue
        //    early; bf_c for THIS chunk stays in flight underneath.
        if (ci < 7) CHANNEL_SECTION(ci + 1)

        // 2) MFMA for chunk ci from s_a[ci&1] (written last region, visible
        //    since the last barrier). bf_n rotation inside as before.
        const uint4* saR = &s_a[P][ci & 1][0];
        #pragma unroll
        for (int kk = 0; kk < 4; ++kk) {
            uint4 bf_n[4];
            if (kk < 3) {
                #pragma unroll
                for (int nt = 0; nt < 4; ++nt)
                    bf_n[nt] = *(const uint4*)(bfrag + ((((size_t)ci * 4 + kk + 1) * 4 + nt) * 64 + lane) * 8);
            }
            short8 af[2];
            #pragma unroll
            for (int m = 0; m < 2; ++m)
                af[m] = __builtin_bit_cast(short8, saR[(2 * h + m) * 257 + kk * 64 + r * 4 + sq]);
            #pragma unroll
            for (int m = 0; m < 2; ++m)
                #pragma unroll
                for (int nt = 0; nt < 4; ++nt)
                    acc[m][nt] = __builtin_amdgcn_mfma_f32_16x16x32_bf16(
                        af[m], __builtin_bit_cast(short8, bf_c[nt]), acc[m][nt], 0, 0, 0);
            #pragma unroll
            for (int nt = 0; nt < 4; ++nt) bf_c[nt] = bf_n[nt];
        }

        // 3) pre-issue next chunk's kk=0 B-frags (consumed only after the NEXT
        //    channel section -> a full region of flight time), then barrier.
        if (ci < 7) {
            #pragma unroll
            for (int nt = 0; nt < 4; ++nt)
                bf_c[nt] = *(const uint4*)(bfrag + ((((size_t)(ci + 1) * 4 + 0) * 4 + nt) * 64 + lane) * 8);
            asm volatile("s_waitcnt lgkmcnt(0)\n\ts_barrier" ::: "memory");
        }
    }
#undef CHANNEL_SECTION

    // ---- epilogue: D col=lane&15 (oc), row=quad*4+reg (point within tile)
    float* yB = y_out + (size_t)b * CC * NN + n0;
    #pragma unroll
    for (int m = 0; m < 2; ++m)
        #pragma unroll
        for (int nt = 0; nt < 4; ++nt) {
            const int oc = nt * 16 + r;
            const float4 v = make_float4(acc[m][nt][0], acc[m][nt][1],
                                         acc[m][nt][2], acc[m][nt][3]);
            *(float4*)(yB + (size_t)oc * NN + (2 * h + m) * 16 + sq * 4) = v;
        }
}

// ---------------------------------------------------------------------------
// Partial batch stats: one block per (b, ch); deterministic.
// ---------------------------------------------------------------------------
__global__ __launch_bounds__(256)
void bn_reduce(const float* __restrict__ y, float* __restrict__ part)
{
    const int ch = blockIdx.x & 63;
    const int b  = blockIdx.x >> 6;
    const int t  = threadIdx.x;
    const float4* p = (const float4*)(y + ((size_t)b * CC + ch) * NN);
    float s = 0.f, ss = 0.f;
    for (int i = t; i < NN / 4; i += 256) {
        const float4 v = p[i];
        s  += v.x + v.y + v.z + v.w;
        ss += v.x * v.x + v.y * v.y + v.z * v.z + v.w * v.w;
    }
    #pragma unroll
    for (int m = 1; m < 64; m <<= 1) {
        s  += __shfl_xor(s, m);
        ss += __shfl_xor(ss, m);
    }
    __shared__ float rs[4], rss[4];
    if ((t & 63) == 0) { rs[t >> 6] = s; rss[t >> 6] = ss; }
    __syncthreads();
    if (t == 0) {
        part[blockIdx.x]       = rs[0] + rs[1] + rs[2] + rs[3];
        part[256 + blockIdx.x] = rss[0] + rss[1] + rss[2] + rss[3];
    }
}

__global__ void bn_stats(const float* __restrict__ part,
                         const float* __restrict__ gamma,
                         const float* __restrict__ beta,
                         float* __restrict__ ab)
{
    const int ch = threadIdx.x;
    float S = 0.f, SS = 0.f;
    #pragma unroll
    for (int b = 0; b < BB; ++b) {
        S  += part[b * 64 + ch];
        SS += part[256 + b * 64 + ch];
    }
    const float inv  = 1.0f / (float)(BB * NN);
    const float mean = S * inv;
    const float var  = SS * inv - mean * mean;
    const float a    = gamma[ch] * rsqrtf(var + 1e-5f);
    ab[ch]      = a;
    ab[CC + ch] = beta[ch] - mean * a;
}

__global__ __launch_bounds__(256)
void bn_apply(float* __restrict__ y, const float* __restrict__ ab)
{
    const size_t i = (size_t)blockIdx.x * 256 + threadIdx.x;  // float4 index
    float4* p = (float4*)y;
    float4 v = p[i];
    const int ch = (int)((i * 4) >> 14) & 63;  // (elem / N) % C
    const float a = ab[ch], bb = ab[CC + ch];
    v.x = fmaxf(fmaf(a, v.x, bb), 0.0f);
    v.y = fmaxf(fmaf(a, v.y, bb), 0.0f);
    v.z = fmaxf(fmaf(a, v.z, bb), 0.0f);
    v.w = fmaxf(fmaf(a, v.w, bb), 0.0f);
    p[i] = v;
}

extern "C" void kernel_launch(void* const* d_in, const int* in_sizes, int n_in,
                              void* d_out, int out_size, void* d_ws, size_t ws_size,
                              hipStream_t stream)
{
    const float* xyz        = (const float*)d_in[0];
    const float* points     = (const float*)d_in[1];
    const float* coordinate = (const float*)d_in[2];
    const float* w1         = (const float*)d_in[3];
    const float* b1         = (const float*)d_in[4];
    const float* lin_w      = (const float*)d_in[5];
    // d_in[6] = lin_b: unused — training-mode BN cancels per-channel shifts
    const float* gamma      = (const float*)d_in[7];
    const float* beta       = (const float*)d_in[8];

    float* out = (float*)d_out;

    // workspace: [0,128K) bfrag bf16; then 512 floats partials; then 128 ab
    unsigned short* bfrag = (unsigned short*)d_ws;
    float* part = (float*)d_ws + 32768;
    float* ab   = part + 512;

    const size_t xyz_elems = (size_t)BB * NN * 3;  // output 0 passthrough
    (void)hipMemcpyAsync(out, xyz, xyz_elems * sizeof(float),
                         hipMemcpyDeviceToDevice, stream);

    float* y_out = out + xyz_elems;  // [B][C][N]

    prep_bfrag<<<32, 256, 0, stream>>>(lin_w, bfrag);
    fused_main<<<BB * (NN / NTB), 256, 0, stream>>>(
        points, coordinate, w1, b1, bfrag, y_out);
    bn_reduce<<<BB * CC, 256, 0, stream>>>(y_out, part);
    bn_stats<<<1, 64, 0, stream>>>(part, gamma, beta, ab);
    bn_apply<<<(BB * CC * NN) / 4 / 256, 256, 0, stream>>>(y_out, ab);
}